// Round 11
// baseline (323.303 us; speedup 1.0000x reference)
//
#include <hip/hip_runtime.h>

typedef __attribute__((ext_vector_type(16))) float f32x16;
typedef __attribute__((ext_vector_type(8))) short bf16x8;

#define AS1 __attribute__((address_space(1)))
#define AS3 __attribute__((address_space(3)))

static __device__ __forceinline__ ushort f2b(float f) {
    uint u = __float_as_uint(f);
    uint r = (u + 0x7fffu + ((u >> 16) & 1u)) >> 16;
    return (ushort)r;
}
static __device__ __forceinline__ float b2f(ushort h) {
    return __uint_as_float(((uint)h) << 16);
}

// ---------------- fp32 -> bf16 convert (vectorized, grid-stride) -------------
__global__ __launch_bounds__(256) void f2b_kernel(const float* __restrict__ in,
                                                  ushort* __restrict__ out, int n4) {
    int i = blockIdx.x * blockDim.x + threadIdx.x;
    int stride = gridDim.x * blockDim.x;
    for (; i < n4; i += stride) {
        float4 v = ((const float4*)in)[i];
        ushort4 o;
        o.x = f2b(v.x); o.y = f2b(v.y); o.z = f2b(v.z); o.w = f2b(v.w);
        ((ushort4*)out)[i] = o;
    }
}

// ---- three equally-sized fp32 arrays -> one contiguous bf16 output ---------
__global__ __launch_bounds__(256) void f2b3_kernel(const float* __restrict__ A,
                                                   const float* __restrict__ B,
                                                   const float* __restrict__ C,
                                                   ushort* __restrict__ out, int n4) {
    int i = blockIdx.x * blockDim.x + threadIdx.x;
    int stride = gridDim.x * blockDim.x;
    for (; i < 3 * n4; i += stride) {
        const float* src = (i < n4) ? A : ((i < 2 * n4) ? B : C);
        int j = (i < n4) ? i : ((i < 2 * n4) ? i - n4 : i - 2 * n4);
        float4 v = ((const float4*)src)[j];
        ushort4 o;
        o.x = f2b(v.x); o.y = f2b(v.y); o.z = f2b(v.z); o.w = f2b(v.w);
        ((ushort4*)out)[i] = o;
    }
}

// ---------------- bf16 GEMM, C = A * B^T, 256x256, BK=64, 4-phase ----------
// R10's proven deep-staged schedule, MFMA shape switched to 32x32x16 (2x
// FLOP/instr, half the instruction count, 2495-TF ceiling vs 2075).
// Per wave (2Mx4N grid): output 128x64 = mf 0..3 (32-row tiles) x nf 0..1.
// Phases = quadrants (mf01/mf23 x nf0/nf1): reads {12,4,8,0} b128, 8 MFMA ea.
// Staging: P1 A-odd(kt+1), P2 A-even(kt+2), P3 B01(kt+2), P4 B23(kt+2);
// ONE vmcnt(6) at P4 seals the next buffer (loads >=3 phases old).
// LDS quarters 64 rows x 64 k (128B/row), chunk swizzle c -> c^(row&7).
__device__ __forceinline__ void stage_q(const ushort* __restrict__ G,
                                        ushort* Ls, int buf, int q, int rc0,
                                        int kcol, int w, int srow, int schunk) {
    ushort* dst = Ls + (buf * 4 + q) * 4096 + w * 512;  // wave-uniform base
    const ushort* src = G + (size_t)(rc0 + q * 64 + srow) * 1024 + kcol + schunk * 8;
    __builtin_amdgcn_global_load_lds((const AS1 void*)src, (AS3 void*)dst, 16, 0, 0);
}

#define PIN_PRE()  do { __builtin_amdgcn_sched_barrier(0); \
                        __builtin_amdgcn_s_barrier(); \
                        asm volatile("s_waitcnt lgkmcnt(0)" ::: "memory"); \
                        __builtin_amdgcn_sched_barrier(0); \
                        __builtin_amdgcn_s_setprio(1); } while (0)
#define PIN_POST() do { __builtin_amdgcn_s_setprio(0); \
                        __builtin_amdgcn_sched_barrier(0); \
                        __builtin_amdgcn_s_barrier(); } while (0)

__global__ __launch_bounds__(512, 2) void gemm_bt8(const ushort* __restrict__ A,
                                                   const ushort* __restrict__ Bw,
                                                   ushort* __restrict__ C) {
    __shared__ ushort SMEM[65536];   // 128 KiB: As | Bs, reused for C epilogue
    ushort* As = SMEM;
    ushort* Bs = SMEM + 32768;

    // T1: XCD-chunked swizzle (nwg = 512)
    int nwg = gridDim.x, cpx = nwg >> 3, bid = blockIdx.x;
    int orig = (bid & 7) * cpx + (bid >> 3);
    int rt = orig >> 2, ct = orig & 3;
    int row0 = rt * 256, col0 = ct * 256;

    int t = threadIdx.x, l = t & 63, w = t >> 6;
    int wr = w >> 2, wc = w & 3;     // wave grid 2 (M) x 4 (N)
    int l31 = l & 31, lhi = l >> 5;

    int srow = t >> 3;                     // staging row within quarter
    int schunk = (l & 7) ^ ((l >> 3) & 7); // staging source 16B chunk
    // read chunk offsets for kstep 0..3 (bytes): ((k*2+lhi) ^ (row&7)) * 16
    int ok[4];
#pragma unroll
    for (int k = 0; k < 4; ++k) ok[k] = (((k * 2 + lhi)) ^ (l31 & 7)) * 16;
    int rbase = l31 * 128;                 // row-in-quarter byte base (l31 part)

    f32x16 acc[4][2] = {};                 // [mf][nf], 32x32 tiles
    bf16x8 a[2][4], b0[4], b1[4];

    const int NT = 16;  // K=1024 / 64
    // prologue: buf0 all 8 quarters; buf1: A q0,q2 + B q0-3
#pragma unroll
    for (int q = 0; q < 4; ++q) stage_q(Bw, Bs, 0, q, col0, 0, w, srow, schunk);
#pragma unroll
    for (int q = 0; q < 4; ++q) stage_q(A, As, 0, q, row0, 0, w, srow, schunk);
    stage_q(A, As, 1, 0, row0, 64, w, srow, schunk);
    stage_q(A, As, 1, 2, row0, 64, w, srow, schunk);
#pragma unroll
    for (int q = 0; q < 4; ++q) stage_q(Bw, Bs, 1, q, col0, 64, w, srow, schunk);
    asm volatile("s_waitcnt vmcnt(6)" ::: "memory");  // seals buf0
    __builtin_amdgcn_s_barrier();

    for (int kt = 0; kt < NT; ++kt) {
        int buf = kt & 1, bn = buf ^ 1;
        int kc1 = (kt + 1) * 64, kc2 = (kt + 2) * 64;
        const char* AqL = (const char*)As + buf * 32768 + (2 * wr) * 8192 + rbase;
        const char* AqH = AqL + 8192;
        const char* Bq  = (const char*)Bs + buf * 32768 + wc * 8192 + rbase;

        // ===== P1 [mf01 x nf0]: read a01(8) + b0(4); stage A-odd(kt+1) ======
#pragma unroll
        for (int mf = 0; mf < 2; ++mf)
#pragma unroll
            for (int k = 0; k < 4; ++k)
                a[mf][k] = *(const bf16x8*)(AqL + mf * 4096 + ok[k]);
#pragma unroll
        for (int k = 0; k < 4; ++k)
            b0[k] = *(const bf16x8*)(Bq + ok[k]);
        if (kt + 1 < NT) {
            stage_q(A, As, bn, 1, row0, kc1, w, srow, schunk);
            stage_q(A, As, bn, 3, row0, kc1, w, srow, schunk);
        }
        asm volatile("s_waitcnt lgkmcnt(8)" ::: "memory");
        PIN_PRE();
#pragma unroll
        for (int k = 0; k < 4; ++k) {
            acc[0][0] = __builtin_amdgcn_mfma_f32_32x32x16_bf16(a[0][k], b0[k], acc[0][0], 0, 0, 0);
            acc[1][0] = __builtin_amdgcn_mfma_f32_32x32x16_bf16(a[1][k], b0[k], acc[1][0], 0, 0, 0);
        }
        PIN_POST();

        // ===== P2 [mf01 x nf1]: read b1(4); stage A-even(kt+2) ==============
#pragma unroll
        for (int k = 0; k < 4; ++k)
            b1[k] = *(const bf16x8*)(Bq + 4096 + ok[k]);
        if (kt + 2 < NT) {
            stage_q(A, As, buf, 0, row0, kc2, w, srow, schunk);
            stage_q(A, As, buf, 2, row0, kc2, w, srow, schunk);
        }
        PIN_PRE();
#pragma unroll
        for (int k = 0; k < 4; ++k) {
            acc[0][1] = __builtin_amdgcn_mfma_f32_32x32x16_bf16(a[0][k], b1[k], acc[0][1], 0, 0, 0);
            acc[1][1] = __builtin_amdgcn_mfma_f32_32x32x16_bf16(a[1][k], b1[k], acc[1][1], 0, 0, 0);
        }
        PIN_POST();

        // ===== P3 [mf23 x nf0]: read a23(8); stage B01(kt+2) ================
#pragma unroll
        for (int mf = 0; mf < 2; ++mf)
#pragma unroll
            for (int k = 0; k < 4; ++k)
                a[mf][k] = *(const bf16x8*)(AqH + mf * 4096 + ok[k]);
        if (kt + 2 < NT) {
            stage_q(Bw, Bs, buf, 0, col0, kc2, w, srow, schunk);
            stage_q(Bw, Bs, buf, 1, col0, kc2, w, srow, schunk);
        }
        PIN_PRE();
#pragma unroll
        for (int k = 0; k < 4; ++k) {
            acc[2][0] = __builtin_amdgcn_mfma_f32_32x32x16_bf16(a[0][k], b0[k], acc[2][0], 0, 0, 0);
            acc[3][0] = __builtin_amdgcn_mfma_f32_32x32x16_bf16(a[1][k], b0[k], acc[3][0], 0, 0, 0);
        }
        PIN_POST();

        // ===== P4 [mf23 x nf1]: stage B23(kt+2); ONE vmcnt checkpoint =======
        if (kt + 2 < NT) {
            stage_q(Bw, Bs, buf, 2, col0, kc2, w, srow, schunk);
            stage_q(Bw, Bs, buf, 3, col0, kc2, w, srow, schunk);
        }
        if (kt + 2 < NT)      asm volatile("s_waitcnt vmcnt(6)" ::: "memory");
        else if (kt + 1 < NT) asm volatile("s_waitcnt vmcnt(0)" ::: "memory");
        __builtin_amdgcn_sched_barrier(0);
        __builtin_amdgcn_s_barrier();
        __builtin_amdgcn_sched_barrier(0);
        __builtin_amdgcn_s_setprio(1);
#pragma unroll
        for (int k = 0; k < 4; ++k) {
            acc[2][1] = __builtin_amdgcn_mfma_f32_32x32x16_bf16(a[0][k], b1[k], acc[2][1], 0, 0, 0);
            acc[3][1] = __builtin_amdgcn_mfma_f32_32x32x16_bf16(a[1][k], b1[k], acc[3][1], 0, 0, 0);
        }
        PIN_POST();
    }

    // ---- epilogue via LDS: 32x32 C/D layout col=l&31,
    //      row=(reg&3)+8*(reg>>2)+4*(l>>5); then coalesced 16B stores ----
#pragma unroll
    for (int mf = 0; mf < 4; ++mf) {
        int lrow0 = wr * 128 + mf * 32;
#pragma unroll
        for (int nf = 0; nf < 2; ++nf) {
            int lcol = wc * 64 + nf * 32 + l31;
#pragma unroll
            for (int r = 0; r < 16; ++r) {
                int lrow = lrow0 + (r & 3) + 8 * (r >> 2) + 4 * lhi;
                SMEM[lrow * 256 + lcol] = f2b(acc[mf][nf][r]);
            }
        }
    }
    __syncthreads();
#pragma unroll
    for (int g = 0; g < 16; ++g) {
        int ch = g * 512 + t;           // 16B-chunk index in the 256x256 tile
        int r = ch >> 5, c8 = ch & 31;
        bf16x8 v = *(const bf16x8*)&SMEM[ch * 8];
        *(bf16x8*)&C[(size_t)(row0 + r) * 1024 + col0 + c8 * 8] = v;
    }
}

// ---------------- gf[b,e] = mean_n( l2norm(K_pre)[n,e] * V[n,e] ) -----------
__global__ __launch_bounds__(256) void kv_reduce(const ushort* __restrict__ Kp,
                                                 const ushort* __restrict__ Vp,
                                                 float* __restrict__ gf) {
    const int D = 1024, N = 4096;
    int b = blockIdx.y;
    int t = threadIdx.x, l = t & 63, w = t >> 6;
    int r0 = blockIdx.x * 128 + w * 32;
    __shared__ float part[4][1024];

    float acc[2][8] = {};
    for (int r = 0; r < 32; ++r) {
        size_t row = (size_t)b * N + r0 + r;
        bf16x8 kv0 = *(const bf16x8*)&Kp[row * D + l * 8];
        bf16x8 kv1 = *(const bf16x8*)&Kp[row * D + l * 8 + 512];
        bf16x8 vv0 = *(const bf16x8*)&Vp[row * D + l * 8];
        bf16x8 vv1 = *(const bf16x8*)&Vp[row * D + l * 8 + 512];
        float kf0[8], kf1[8], ss = 0.f;
#pragma unroll
        for (int j = 0; j < 8; ++j) {
            kf0[j] = b2f((ushort)kv0[j]);
            kf1[j] = b2f((ushort)kv1[j]);
            ss += kf0[j] * kf0[j] + kf1[j] * kf1[j];
        }
#pragma unroll
        for (int off = 32; off; off >>= 1) ss += __shfl_xor(ss, off);
        float inv = 1.0f / fmaxf(sqrtf(ss), 1e-12f);
#pragma unroll
        for (int j = 0; j < 8; ++j) {
            acc[0][j] += kf0[j] * inv * b2f((ushort)vv0[j]);
            acc[1][j] += kf1[j] * inv * b2f((ushort)vv1[j]);
        }
    }
#pragma unroll
    for (int i = 0; i < 2; ++i)
#pragma unroll
        for (int j = 0; j < 8; ++j)
            part[w][l * 8 + i * 512 + j] = acc[i][j];
    __syncthreads();
    const float sc = 1.0f / 4096.0f;
#pragma unroll
    for (int i = 0; i < 4; ++i) {
        int c = t * 4 + i;
        float s = part[0][c] + part[1][c] + part[2][c] + part[3][c];
        atomicAdd(&gf[b * D + c], s * sc);
    }
}

// ---------------- out[row,e] = l2norm(Q_pre)[row,e] * gf[b,e]  (fp32 out) ---
__global__ __launch_bounds__(256) void q_scale(const ushort* __restrict__ Qp,
                                               const float* __restrict__ gf,
                                               float* __restrict__ out) {
    const int D = 1024;
    int row = blockIdx.x * 4 + (threadIdx.x >> 6);
    int l = threadIdx.x & 63;
    int b = row >> 12;
    const ushort* qr = &Qp[(size_t)row * D];
    float qf[4][4];
    float ss = 0.f;
#pragma unroll
    for (int i = 0; i < 4; ++i) {
        ushort4 q = *(const ushort4*)&qr[l * 4 + i * 256];
        qf[i][0] = b2f(q.x); qf[i][1] = b2f(q.y);
        qf[i][2] = b2f(q.z); qf[i][3] = b2f(q.w);
        ss += qf[i][0] * qf[i][0] + qf[i][1] * qf[i][1] +
              qf[i][2] * qf[i][2] + qf[i][3] * qf[i][3];
    }
#pragma unroll
    for (int off = 32; off; off >>= 1) ss += __shfl_xor(ss, off);
    float inv = 1.0f / fmaxf(sqrtf(ss), 1e-12f);
#pragma unroll
    for (int i = 0; i < 4; ++i) {
        float4 g = *(const float4*)&gf[b * D + l * 4 + i * 256];
        float4 o;
        o.x = qf[i][0] * inv * g.x;
        o.y = qf[i][1] * inv * g.y;
        o.z = qf[i][2] * inv * g.z;
        o.w = qf[i][3] * inv * g.w;
        *(float4*)&out[(size_t)row * D + l * 4 + i * 256] = o;
    }
}

extern "C" void kernel_launch(void* const* d_in, const int* in_sizes, int n_in,
                              void* d_out, int out_size, void* d_ws, size_t ws_size,
                              hipStream_t stream) {
    const float* x  = (const float*)d_in[0];
    const float* Wq = (const float*)d_in[1];
    const float* Wk = (const float*)d_in[2];
    const float* Wv = (const float*)d_in[3];
    float* out = (float*)d_out;

    const int Bb = 8, Nn = 4096, D = 1024;
    const int M = Bb * Nn;  // 32768 rows

    char* ws = (char*)d_ws;
    ushort* xb  = (ushort*)ws;                         // 67108864 B
    ushort* wqb = (ushort*)(ws + 67108864);            // 2097152 B  } contiguous
    ushort* wkb = (ushort*)(ws + 69206016);            // 2097152 B  } bf16 W's
    ushort* wvb = (ushort*)(ws + 71303168);            // 2097152 B  }
    ushort* P1  = (ushort*)(ws + 73400320);            // 67108864 B (Q_pre)
    float*  gf  = (float*)(ws + 140509184);            // 32768 B

    // d_out (134.2 MB) doubles as bf16 scratch for K_pre / V until q_scale.
    ushort* Kp = (ushort*)d_out;
    ushort* Vp = Kp + (size_t)M * D;

    hipMemsetAsync(gf, 0, Bb * D * sizeof(float), stream);

    f2b_kernel<<<2048, 256, 0, stream>>>(x, xb, (M * D) / 4);
    f2b3_kernel<<<1536, 256, 0, stream>>>(Wq, Wk, Wv, wqb, (D * D) / 4);

    gemm_bt8<<<512, 512, 0, stream>>>(xb, wkb, Kp);
    gemm_bt8<<<512, 512, 0, stream>>>(xb, wvb, Vp);
    kv_reduce<<<dim3(32, 8), 256, 0, stream>>>(Kp, Vp, gf);
    gemm_bt8<<<512, 512, 0, stream>>>(xb, wqb, P1);
    q_scale<<<M / 4, 256, 0, stream>>>(P1, gf, out);
}

// Round 12
// 310.421 us; speedup vs baseline: 1.0415x; 1.0415x over previous
//
#include <hip/hip_runtime.h>

typedef __attribute__((ext_vector_type(4))) float f32x4;
typedef __attribute__((ext_vector_type(8))) short bf16x8;

#define AS1 __attribute__((address_space(1)))
#define AS3 __attribute__((address_space(3)))

static __device__ __forceinline__ ushort f2b(float f) {
    uint u = __float_as_uint(f);
    uint r = (u + 0x7fffu + ((u >> 16) & 1u)) >> 16;
    return (ushort)r;
}
static __device__ __forceinline__ float b2f(ushort h) {
    return __uint_as_float(((uint)h) << 16);
}

// ---------------- fp32 -> bf16 convert (vectorized, grid-stride) -------------
__global__ __launch_bounds__(256) void f2b_kernel(const float* __restrict__ in,
                                                  ushort* __restrict__ out, int n4) {
    int i = blockIdx.x * blockDim.x + threadIdx.x;
    int stride = gridDim.x * blockDim.x;
    for (; i < n4; i += stride) {
        float4 v = ((const float4*)in)[i];
        ushort4 o;
        o.x = f2b(v.x); o.y = f2b(v.y); o.z = f2b(v.z); o.w = f2b(v.w);
        ((ushort4*)out)[i] = o;
    }
}

// ---- three equally-sized fp32 arrays -> one contiguous bf16 output ---------
__global__ __launch_bounds__(256) void f2b3_kernel(const float* __restrict__ A,
                                                   const float* __restrict__ B,
                                                   const float* __restrict__ C,
                                                   ushort* __restrict__ out, int n4) {
    int i = blockIdx.x * blockDim.x + threadIdx.x;
    int stride = gridDim.x * blockDim.x;
    for (; i < 3 * n4; i += stride) {
        const float* src = (i < n4) ? A : ((i < 2 * n4) ? B : C);
        int j = (i < n4) ? i : ((i < 2 * n4) ? i - n4 : i - 2 * n4);
        float4 v = ((const float4*)src)[j];
        ushort4 o;
        o.x = f2b(v.x); o.y = f2b(v.y); o.z = f2b(v.z); o.w = f2b(v.w);
        ((ushort4*)out)[i] = o;
    }
}

// ---------------- bf16 GEMM, C = A * B^T, 256x256, BK=64, TWO-phase --------
// R10's deep-staged schedule with quadrant pairs merged: 2 phases/K-tile,
// 32-MFMA clusters. Ph1 = m-lo x n-all (reads a-lo 8 + b-all 8; stages
// A-odd(kt+1)); Ph2 = m-hi x n-all (reads a-hi 8; b held in regs; stages
// A-even(kt+2) + B q0-3(kt+2); ONE vmcnt(6) seals buf(kt+1)).
// Safety: each staged slot's last reader is in the OTHER phase (A-odd
// read@Ph2 / staged@Ph1; A-even,B read@Ph1 / staged@Ph2) -> barrier-separated.
// vmcnt ledger: carried 6 + issued 8 = 14 -> vmcnt(6) drains exactly the 8
// sealing buf(kt+1), leaves {A-even,B}(kt+2) = 6 (same invariant as R10).
__device__ __forceinline__ void stage_q(const ushort* __restrict__ G,
                                        ushort* Ls, int buf, int q, int rc0,
                                        int kcol, int w, int srow, int schunk) {
    ushort* dst = Ls + (buf * 4 + q) * 4096 + w * 512;  // wave-uniform base
    const ushort* src = G + (size_t)(rc0 + q * 64 + srow) * 1024 + kcol + schunk * 8;
    __builtin_amdgcn_global_load_lds((const AS1 void*)src, (AS3 void*)dst, 16, 0, 0);
}

#define PIN_PRE()  do { __builtin_amdgcn_sched_barrier(0); \
                        __builtin_amdgcn_s_barrier(); \
                        asm volatile("s_waitcnt lgkmcnt(0)" ::: "memory"); \
                        __builtin_amdgcn_sched_barrier(0); \
                        __builtin_amdgcn_s_setprio(1); } while (0)
#define PIN_POST() do { __builtin_amdgcn_s_setprio(0); \
                        __builtin_amdgcn_sched_barrier(0); \
                        __builtin_amdgcn_s_barrier(); } while (0)

__global__ __launch_bounds__(512, 2) void gemm_bt9(const ushort* __restrict__ A,
                                                   const ushort* __restrict__ Bw,
                                                   ushort* __restrict__ C) {
    __shared__ ushort SMEM[65536];   // 128 KiB: As | Bs, reused for C epilogue
    ushort* As = SMEM;
    ushort* Bs = SMEM + 32768;

    // T1: XCD-chunked swizzle (nwg = 512)
    int nwg = gridDim.x, cpx = nwg >> 3, bid = blockIdx.x;
    int orig = (bid & 7) * cpx + (bid >> 3);
    int rt = orig >> 2, ct = orig & 3;
    int row0 = rt * 256, col0 = ct * 256;

    int t = threadIdx.x, l = t & 63, w = t >> 6;
    int wr = w >> 2, wc = w & 3;     // wave grid 2 (M) x 4 (N)
    int lr = l & 15, c16 = l >> 4;

    int srow = t >> 3;                     // staging row within quarter
    int schunk = (l & 7) ^ ((l >> 3) & 7); // staging source 16B chunk
    int o0 = ((c16 ^ (l & 7))) * 16;       // read slot bytes, k=0
    int o1 = o0 ^ 64;                      // k=1

    f32x4 acc[8][4] = {};
    bf16x8 a[4], a2[4], b[4][2];

    const int NT = 16;  // K=1024 / 64
    // prologue: buf0 all 8 quarters; buf1: A-even (q0,q2) + B q0-3
#pragma unroll
    for (int q = 0; q < 4; ++q) stage_q(Bw, Bs, 0, q, col0, 0, w, srow, schunk);
#pragma unroll
    for (int q = 0; q < 4; ++q) stage_q(A, As, 0, q, row0, 0, w, srow, schunk);
    stage_q(A, As, 1, 0, row0, 64, w, srow, schunk);
    stage_q(A, As, 1, 2, row0, 64, w, srow, schunk);
#pragma unroll
    for (int q = 0; q < 4; ++q) stage_q(Bw, Bs, 1, q, col0, 64, w, srow, schunk);
    asm volatile("s_waitcnt vmcnt(6)" ::: "memory");  // seals buf0
    __builtin_amdgcn_s_barrier();

    for (int kt = 0; kt < NT; ++kt) {
        int buf = kt & 1, bn = buf ^ 1;
        int kc1 = (kt + 1) * 64, kc2 = (kt + 2) * 64;
        const char* AqL = (const char*)As + buf * 32768 + (2 * wr) * 8192 + lr * 128;
        const char* AqH = AqL + 8192;
        const char* Bq  = (const char*)Bs + buf * 32768 + wc * 8192 + lr * 128;

        // ===== Ph1 [m-lo x n-all]: read a-lo(8) + b-all(8); stage A-odd(kt+1)
#pragma unroll
        for (int mf = 0; mf < 4; ++mf) {
            a[mf]  = *(const bf16x8*)(AqL + mf * 2048 + o0);
            a2[mf] = *(const bf16x8*)(AqL + mf * 2048 + o1);
        }
#pragma unroll
        for (int nf = 0; nf < 4; ++nf) {
            b[nf][0] = *(const bf16x8*)(Bq + nf * 2048 + o0);
            b[nf][1] = *(const bf16x8*)(Bq + nf * 2048 + o1);
        }
        if (kt + 1 < NT) {
            stage_q(A, As, bn, 1, row0, kc1, w, srow, schunk);
            stage_q(A, As, bn, 3, row0, kc1, w, srow, schunk);
        }
        asm volatile("s_waitcnt lgkmcnt(8)" ::: "memory");
        PIN_PRE();
#pragma unroll
        for (int mf = 0; mf < 4; ++mf)
#pragma unroll
            for (int nf = 0; nf < 4; ++nf) {
                acc[mf][nf] = __builtin_amdgcn_mfma_f32_16x16x32_bf16(a[mf],  b[nf][0], acc[mf][nf], 0, 0, 0);
                acc[mf][nf] = __builtin_amdgcn_mfma_f32_16x16x32_bf16(a2[mf], b[nf][1], acc[mf][nf], 0, 0, 0);
            }
        PIN_POST();

        // ===== Ph2 [m-hi x n-all]: read a-hi(8); stage A-even(kt+2) +
        //       B q0-3(kt+2); ONE vmcnt checkpoint ============================
#pragma unroll
        for (int mf = 0; mf < 4; ++mf) {
            a[mf]  = *(const bf16x8*)(AqH + mf * 2048 + o0);
            a2[mf] = *(const bf16x8*)(AqH + mf * 2048 + o1);
        }
        if (kt + 2 < NT) {
            stage_q(A, As, buf, 0, row0, kc2, w, srow, schunk);
            stage_q(A, As, buf, 2, row0, kc2, w, srow, schunk);
            stage_q(Bw, Bs, buf, 0, col0, kc2, w, srow, schunk);
            stage_q(Bw, Bs, buf, 1, col0, kc2, w, srow, schunk);
            stage_q(Bw, Bs, buf, 2, col0, kc2, w, srow, schunk);
            stage_q(Bw, Bs, buf, 3, col0, kc2, w, srow, schunk);
        }
        if (kt + 2 < NT)      asm volatile("s_waitcnt vmcnt(6)" ::: "memory");
        else if (kt + 1 < NT) asm volatile("s_waitcnt vmcnt(0)" ::: "memory");
        PIN_PRE();
#pragma unroll
        for (int mf = 0; mf < 4; ++mf)
#pragma unroll
            for (int nf = 0; nf < 4; ++nf) {
                acc[4 + mf][nf] = __builtin_amdgcn_mfma_f32_16x16x32_bf16(a[mf],  b[nf][0], acc[4 + mf][nf], 0, 0, 0);
                acc[4 + mf][nf] = __builtin_amdgcn_mfma_f32_16x16x32_bf16(a2[mf], b[nf][1], acc[4 + mf][nf], 0, 0, 0);
            }
        PIN_POST();
    }

    // ---- epilogue via LDS: scalar ds_writes, coalesced 16B global stores ----
#pragma unroll
    for (int m = 0; m < 8; ++m) {
        int lrow = wr * 128 + m * 16 + c16 * 4;
#pragma unroll
        for (int n = 0; n < 4; ++n) {
            int lcol = wc * 64 + n * 16 + lr;
#pragma unroll
            for (int j = 0; j < 4; ++j)
                SMEM[(lrow + j) * 256 + lcol] = f2b(acc[m][n][j]);
        }
    }
    __syncthreads();
#pragma unroll
    for (int g = 0; g < 16; ++g) {
        int ch = g * 512 + t;           // 16B-chunk index in the 256x256 tile
        int r = ch >> 5, c8 = ch & 31;
        bf16x8 v = *(const bf16x8*)&SMEM[ch * 8];
        *(bf16x8*)&C[(size_t)(row0 + r) * 1024 + col0 + c8 * 8] = v;
    }
}

// ---------------- gf[b,e] = mean_n( l2norm(K_pre)[n,e] * V[n,e] ) -----------
__global__ __launch_bounds__(256) void kv_reduce(const ushort* __restrict__ Kp,
                                                 const ushort* __restrict__ Vp,
                                                 float* __restrict__ gf) {
    const int D = 1024, N = 4096;
    int b = blockIdx.y;
    int t = threadIdx.x, l = t & 63, w = t >> 6;
    int r0 = blockIdx.x * 128 + w * 32;
    __shared__ float part[4][1024];

    float acc[2][8] = {};
    for (int r = 0; r < 32; ++r) {
        size_t row = (size_t)b * N + r0 + r;
        bf16x8 kv0 = *(const bf16x8*)&Kp[row * D + l * 8];
        bf16x8 kv1 = *(const bf16x8*)&Kp[row * D + l * 8 + 512];
        bf16x8 vv0 = *(const bf16x8*)&Vp[row * D + l * 8];
        bf16x8 vv1 = *(const bf16x8*)&Vp[row * D + l * 8 + 512];
        float kf0[8], kf1[8], ss = 0.f;
#pragma unroll
        for (int j = 0; j < 8; ++j) {
            kf0[j] = b2f((ushort)kv0[j]);
            kf1[j] = b2f((ushort)kv1[j]);
            ss += kf0[j] * kf0[j] + kf1[j] * kf1[j];
        }
#pragma unroll
        for (int off = 32; off; off >>= 1) ss += __shfl_xor(ss, off);
        float inv = 1.0f / fmaxf(sqrtf(ss), 1e-12f);
#pragma unroll
        for (int j = 0; j < 8; ++j) {
            acc[0][j] += kf0[j] * inv * b2f((ushort)vv0[j]);
            acc[1][j] += kf1[j] * inv * b2f((ushort)vv1[j]);
        }
    }
#pragma unroll
    for (int i = 0; i < 2; ++i)
#pragma unroll
        for (int j = 0; j < 8; ++j)
            part[w][l * 8 + i * 512 + j] = acc[i][j];
    __syncthreads();
    const float sc = 1.0f / 4096.0f;
#pragma unroll
    for (int i = 0; i < 4; ++i) {
        int c = t * 4 + i;
        float s = part[0][c] + part[1][c] + part[2][c] + part[3][c];
        atomicAdd(&gf[b * D + c], s * sc);
    }
}

// ---------------- out[row,e] = l2norm(Q_pre)[row,e] * gf[b,e]  (fp32 out) ---
__global__ __launch_bounds__(256) void q_scale(const ushort* __restrict__ Qp,
                                               const float* __restrict__ gf,
                                               float* __restrict__ out) {
    const int D = 1024;
    int row = blockIdx.x * 4 + (threadIdx.x >> 6);
    int l = threadIdx.x & 63;
    int b = row >> 12;
    const ushort* qr = &Qp[(size_t)row * D];
    float qf[4][4];
    float ss = 0.f;
#pragma unroll
    for (int i = 0; i < 4; ++i) {
        ushort4 q = *(const ushort4*)&qr[l * 4 + i * 256];
        qf[i][0] = b2f(q.x); qf[i][1] = b2f(q.y);
        qf[i][2] = b2f(q.z); qf[i][3] = b2f(q.w);
        ss += qf[i][0] * qf[i][0] + qf[i][1] * qf[i][1] +
              qf[i][2] * qf[i][2] + qf[i][3] * qf[i][3];
    }
#pragma unroll
    for (int off = 32; off; off >>= 1) ss += __shfl_xor(ss, off);
    float inv = 1.0f / fmaxf(sqrtf(ss), 1e-12f);
#pragma unroll
    for (int i = 0; i < 4; ++i) {
        float4 g = *(const float4*)&gf[b * D + l * 4 + i * 256];
        float4 o;
        o.x = qf[i][0] * inv * g.x;
        o.y = qf[i][1] * inv * g.y;
        o.z = qf[i][2] * inv * g.z;
        o.w = qf[i][3] * inv * g.w;
        *(float4*)&out[(size_t)row * D + l * 4 + i * 256] = o;
    }
}

extern "C" void kernel_launch(void* const* d_in, const int* in_sizes, int n_in,
                              void* d_out, int out_size, void* d_ws, size_t ws_size,
                              hipStream_t stream) {
    const float* x  = (const float*)d_in[0];
    const float* Wq = (const float*)d_in[1];
    const float* Wk = (const float*)d_in[2];
    const float* Wv = (const float*)d_in[3];
    float* out = (float*)d_out;

    const int Bb = 8, Nn = 4096, D = 1024;
    const int M = Bb * Nn;  // 32768 rows

    char* ws = (char*)d_ws;
    ushort* xb  = (ushort*)ws;                         // 67108864 B
    ushort* wqb = (ushort*)(ws + 67108864);            // 2097152 B  } contiguous
    ushort* wkb = (ushort*)(ws + 69206016);            // 2097152 B  } bf16 W's
    ushort* wvb = (ushort*)(ws + 71303168);            // 2097152 B  }
    ushort* P1  = (ushort*)(ws + 73400320);            // 67108864 B (Q_pre)
    float*  gf  = (float*)(ws + 140509184);            // 32768 B

    // d_out (134.2 MB) doubles as bf16 scratch for K_pre / V until q_scale.
    ushort* Kp = (ushort*)d_out;
    ushort* Vp = Kp + (size_t)M * D;

    hipMemsetAsync(gf, 0, Bb * D * sizeof(float), stream);

    f2b_kernel<<<2048, 256, 0, stream>>>(x, xb, (M * D) / 4);
    f2b3_kernel<<<1536, 256, 0, stream>>>(Wq, Wk, Wv, wqb, (D * D) / 4);

    gemm_bt9<<<512, 512, 0, stream>>>(xb, wkb, Kp);
    gemm_bt9<<<512, 512, 0, stream>>>(xb, wvb, Vp);
    kv_reduce<<<dim3(32, 8), 256, 0, stream>>>(Kp, Vp, gf);
    gemm_bt9<<<512, 512, 0, stream>>>(xb, wqb, P1);
    q_scale<<<M / 4, 256, 0, stream>>>(P1, gf, out);
}

// Round 13
// 302.105 us; speedup vs baseline: 1.0702x; 1.0275x over previous
//
#include <hip/hip_runtime.h>

typedef __attribute__((ext_vector_type(4))) float f32x4;
typedef __attribute__((ext_vector_type(8))) short bf16x8;

#define AS1 __attribute__((address_space(1)))
#define AS3 __attribute__((address_space(3)))

static __device__ __forceinline__ ushort f2b(float f) {
    uint u = __float_as_uint(f);
    uint r = (u + 0x7fffu + ((u >> 16) & 1u)) >> 16;
    return (ushort)r;
}
static __device__ __forceinline__ float b2f(ushort h) {
    return __uint_as_float(((uint)h) << 16);
}

// ---------------- fp32 -> bf16 convert (vectorized, grid-stride) -------------
__global__ __launch_bounds__(256) void f2b_kernel(const float* __restrict__ in,
                                                  ushort* __restrict__ out, int n4) {
    int i = blockIdx.x * blockDim.x + threadIdx.x;
    int stride = gridDim.x * blockDim.x;
    for (; i < n4; i += stride) {
        float4 v = ((const float4*)in)[i];
        ushort4 o;
        o.x = f2b(v.x); o.y = f2b(v.y); o.z = f2b(v.z); o.w = f2b(v.w);
        ((ushort4*)out)[i] = o;
    }
}

// ---- three equally-sized fp32 arrays -> one contiguous bf16 output ---------
__global__ __launch_bounds__(256) void f2b3_kernel(const float* __restrict__ A,
                                                   const float* __restrict__ B,
                                                   const float* __restrict__ C,
                                                   ushort* __restrict__ out, int n4) {
    int i = blockIdx.x * blockDim.x + threadIdx.x;
    int stride = gridDim.x * blockDim.x;
    for (; i < 3 * n4; i += stride) {
        const float* src = (i < n4) ? A : ((i < 2 * n4) ? B : C);
        int j = (i < n4) ? i : ((i < 2 * n4) ? i - n4 : i - 2 * n4);
        float4 v = ((const float4*)src)[j];
        ushort4 o;
        o.x = f2b(v.x); o.y = f2b(v.y); o.z = f2b(v.z); o.w = f2b(v.w);
        ((ushort4*)out)[i] = o;
    }
}

// ---------------- bf16 GEMM, C = A * B^T, 256x256, BK=64, 4-phase ----------
// R10's deep-staged schedule with ALL sched_barrier(0) pins REMOVED
// (m141 evidence: SGB order-pinning defeats the compiler's interleave and
// cost -40% on a working GEMM; the m201 template's K-loop has none).
// Phase boundary = { [lgkmcnt(8) if 12 reads]; s_barrier; lgkmcnt(0);
// setprio(1); MFMA cluster; setprio(0); s_barrier } — m201-canonical.
// Staging: P1 A-odd(kt+1), P2 A-even(kt+2), P3 B01(kt+2), P4 B23(kt+2);
// ONE vmcnt(6) at P4 seals buf(kt+1) (loads >=3 phases old).
__device__ __forceinline__ void stage_q(const ushort* __restrict__ G,
                                        ushort* Ls, int buf, int q, int rc0,
                                        int kcol, int w, int srow, int schunk) {
    ushort* dst = Ls + (buf * 4 + q) * 4096 + w * 512;  // wave-uniform base
    const ushort* src = G + (size_t)(rc0 + q * 64 + srow) * 1024 + kcol + schunk * 8;
    __builtin_amdgcn_global_load_lds((const AS1 void*)src, (AS3 void*)dst, 16, 0, 0);
}

#define PIN_PRE()  do { __builtin_amdgcn_s_barrier(); \
                        asm volatile("s_waitcnt lgkmcnt(0)" ::: "memory"); \
                        __builtin_amdgcn_s_setprio(1); } while (0)
#define PIN_POST() do { __builtin_amdgcn_s_setprio(0); \
                        __builtin_amdgcn_s_barrier(); } while (0)

__global__ __launch_bounds__(512, 2) void gemm_bt10(const ushort* __restrict__ A,
                                                    const ushort* __restrict__ Bw,
                                                    ushort* __restrict__ C) {
    __shared__ ushort SMEM[65536];   // 128 KiB: As | Bs, reused for C epilogue
    ushort* As = SMEM;
    ushort* Bs = SMEM + 32768;

    // T1: XCD-chunked swizzle (nwg = 512)
    int nwg = gridDim.x, cpx = nwg >> 3, bid = blockIdx.x;
    int orig = (bid & 7) * cpx + (bid >> 3);
    int rt = orig >> 2, ct = orig & 3;
    int row0 = rt * 256, col0 = ct * 256;

    int t = threadIdx.x, l = t & 63, w = t >> 6;
    int wr = w >> 2, wc = w & 3;     // wave grid 2 (M) x 4 (N)
    int lr = l & 15, c16 = l >> 4;

    int srow = t >> 3;                     // staging row within quarter
    int schunk = (l & 7) ^ ((l >> 3) & 7); // staging source 16B chunk
    int o0 = ((c16 ^ (l & 7))) * 16;       // read slot bytes, k=0
    int o1 = o0 ^ 64;                      // k=1

    f32x4 acc[8][4] = {};
    bf16x8 a[4], a2[4], blo[2][2], bhi[2][2];

    const int NT = 16;  // K=1024 / 64
    // prologue: buf0 all 8 quarters; buf1: A-even (q0,q2) + B q0-3
#pragma unroll
    for (int q = 0; q < 4; ++q) stage_q(Bw, Bs, 0, q, col0, 0, w, srow, schunk);
#pragma unroll
    for (int q = 0; q < 4; ++q) stage_q(A, As, 0, q, row0, 0, w, srow, schunk);
    stage_q(A, As, 1, 0, row0, 64, w, srow, schunk);
    stage_q(A, As, 1, 2, row0, 64, w, srow, schunk);
#pragma unroll
    for (int q = 0; q < 4; ++q) stage_q(Bw, Bs, 1, q, col0, 64, w, srow, schunk);
    asm volatile("s_waitcnt vmcnt(6)" ::: "memory");  // seals buf0
    __builtin_amdgcn_s_barrier();

    for (int kt = 0; kt < NT; ++kt) {
        int buf = kt & 1, bn = buf ^ 1;
        int kc1 = (kt + 1) * 64, kc2 = (kt + 2) * 64;
        const char* AqL = (const char*)As + buf * 32768 + (2 * wr) * 8192 + lr * 128;
        const char* AqH = AqL + 8192;
        const char* Bq  = (const char*)Bs + buf * 32768 + wc * 8192 + lr * 128;

        // ===== P1 [mlo x nlo]: read a-lo(8) + b-lo(4); stage A-odd(kt+1) ====
#pragma unroll
        for (int mf = 0; mf < 4; ++mf) {
            a[mf]  = *(const bf16x8*)(AqL + mf * 2048 + o0);
            a2[mf] = *(const bf16x8*)(AqL + mf * 2048 + o1);
        }
#pragma unroll
        for (int nf = 0; nf < 2; ++nf) {
            blo[nf][0] = *(const bf16x8*)(Bq + nf * 2048 + o0);
            blo[nf][1] = *(const bf16x8*)(Bq + nf * 2048 + o1);
        }
        if (kt + 1 < NT) {
            stage_q(A, As, bn, 1, row0, kc1, w, srow, schunk);
            stage_q(A, As, bn, 3, row0, kc1, w, srow, schunk);
        }
        asm volatile("s_waitcnt lgkmcnt(8)" ::: "memory");
        PIN_PRE();
#pragma unroll
        for (int mf = 0; mf < 4; ++mf)
#pragma unroll
            for (int nf = 0; nf < 2; ++nf) {
                acc[mf][nf] = __builtin_amdgcn_mfma_f32_16x16x32_bf16(a[mf],  blo[nf][0], acc[mf][nf], 0, 0, 0);
                acc[mf][nf] = __builtin_amdgcn_mfma_f32_16x16x32_bf16(a2[mf], blo[nf][1], acc[mf][nf], 0, 0, 0);
            }
        PIN_POST();

        // ===== P2 [mlo x nhi]: read b-hi(4); stage A-even(kt+2) =============
#pragma unroll
        for (int nf = 0; nf < 2; ++nf) {
            bhi[nf][0] = *(const bf16x8*)(Bq + (2 + nf) * 2048 + o0);
            bhi[nf][1] = *(const bf16x8*)(Bq + (2 + nf) * 2048 + o1);
        }
        if (kt + 2 < NT) {
            stage_q(A, As, buf, 0, row0, kc2, w, srow, schunk);
            stage_q(A, As, buf, 2, row0, kc2, w, srow, schunk);
        }
        PIN_PRE();
#pragma unroll
        for (int mf = 0; mf < 4; ++mf)
#pragma unroll
            for (int nf = 0; nf < 2; ++nf) {
                acc[mf][2 + nf] = __builtin_amdgcn_mfma_f32_16x16x32_bf16(a[mf],  bhi[nf][0], acc[mf][2 + nf], 0, 0, 0);
                acc[mf][2 + nf] = __builtin_amdgcn_mfma_f32_16x16x32_bf16(a2[mf], bhi[nf][1], acc[mf][2 + nf], 0, 0, 0);
            }
        PIN_POST();

        // ===== P3 [mhi x nlo]: read a-hi(8); stage B01(kt+2) ================
#pragma unroll
        for (int mf = 0; mf < 4; ++mf) {
            a[mf]  = *(const bf16x8*)(AqH + mf * 2048 + o0);
            a2[mf] = *(const bf16x8*)(AqH + mf * 2048 + o1);
        }
        if (kt + 2 < NT) {
            stage_q(Bw, Bs, buf, 0, col0, kc2, w, srow, schunk);
            stage_q(Bw, Bs, buf, 1, col0, kc2, w, srow, schunk);
        }
        PIN_PRE();
#pragma unroll
        for (int mf = 0; mf < 4; ++mf)
#pragma unroll
            for (int nf = 0; nf < 2; ++nf) {
                acc[4 + mf][nf] = __builtin_amdgcn_mfma_f32_16x16x32_bf16(a[mf],  blo[nf][0], acc[4 + mf][nf], 0, 0, 0);
                acc[4 + mf][nf] = __builtin_amdgcn_mfma_f32_16x16x32_bf16(a2[mf], blo[nf][1], acc[4 + mf][nf], 0, 0, 0);
            }
        PIN_POST();

        // ===== P4 [mhi x nhi]: stage B23(kt+2); ONE vmcnt checkpoint ========
        if (kt + 2 < NT) {
            stage_q(Bw, Bs, buf, 2, col0, kc2, w, srow, schunk);
            stage_q(Bw, Bs, buf, 3, col0, kc2, w, srow, schunk);
        }
        if (kt + 2 < NT)      asm volatile("s_waitcnt vmcnt(6)" ::: "memory");
        else if (kt + 1 < NT) asm volatile("s_waitcnt vmcnt(0)" ::: "memory");
        __builtin_amdgcn_s_barrier();
        __builtin_amdgcn_s_setprio(1);
#pragma unroll
        for (int mf = 0; mf < 4; ++mf)
#pragma unroll
            for (int nf = 0; nf < 2; ++nf) {
                acc[4 + mf][2 + nf] = __builtin_amdgcn_mfma_f32_16x16x32_bf16(a[mf],  bhi[nf][0], acc[4 + mf][2 + nf], 0, 0, 0);
                acc[4 + mf][2 + nf] = __builtin_amdgcn_mfma_f32_16x16x32_bf16(a2[mf], bhi[nf][1], acc[4 + mf][2 + nf], 0, 0, 0);
            }
        PIN_POST();
    }

    // ---- epilogue via LDS: scalar ds_writes, coalesced 16B global stores ----
#pragma unroll
    for (int m = 0; m < 8; ++m) {
        int lrow = wr * 128 + m * 16 + c16 * 4;
#pragma unroll
        for (int n = 0; n < 4; ++n) {
            int lcol = wc * 64 + n * 16 + lr;
#pragma unroll
            for (int j = 0; j < 4; ++j)
                SMEM[(lrow + j) * 256 + lcol] = f2b(acc[m][n][j]);
        }
    }
    __syncthreads();
#pragma unroll
    for (int g = 0; g < 16; ++g) {
        int ch = g * 512 + t;           // 16B-chunk index in the 256x256 tile
        int r = ch >> 5, c8 = ch & 31;
        bf16x8 v = *(const bf16x8*)&SMEM[ch * 8];
        *(bf16x8*)&C[(size_t)(row0 + r) * 1024 + col0 + c8 * 8] = v;
    }
}

// ---------------- gf[b,e] = mean_n( l2norm(K_pre)[n,e] * V[n,e] ) -----------
__global__ __launch_bounds__(256) void kv_reduce(const ushort* __restrict__ Kp,
                                                 const ushort* __restrict__ Vp,
                                                 float* __restrict__ gf) {
    const int D = 1024, N = 4096;
    int b = blockIdx.y;
    int t = threadIdx.x, l = t & 63, w = t >> 6;
    int r0 = blockIdx.x * 128 + w * 32;
    __shared__ float part[4][1024];

    float acc[2][8] = {};
    for (int r = 0; r < 32; ++r) {
        size_t row = (size_t)b * N + r0 + r;
        bf16x8 kv0 = *(const bf16x8*)&Kp[row * D + l * 8];
        bf16x8 kv1 = *(const bf16x8*)&Kp[row * D + l * 8 + 512];
        bf16x8 vv0 = *(const bf16x8*)&Vp[row * D + l * 8];
        bf16x8 vv1 = *(const bf16x8*)&Vp[row * D + l * 8 + 512];
        float kf0[8], kf1[8], ss = 0.f;
#pragma unroll
        for (int j = 0; j < 8; ++j) {
            kf0[j] = b2f((ushort)kv0[j]);
            kf1[j] = b2f((ushort)kv1[j]);
            ss += kf0[j] * kf0[j] + kf1[j] * kf1[j];
        }
#pragma unroll
        for (int off = 32; off; off >>= 1) ss += __shfl_xor(ss, off);
        float inv = 1.0f / fmaxf(sqrtf(ss), 1e-12f);
#pragma unroll
        for (int j = 0; j < 8; ++j) {
            acc[0][j] += kf0[j] * inv * b2f((ushort)vv0[j]);
            acc[1][j] += kf1[j] * inv * b2f((ushort)vv1[j]);
        }
    }
#pragma unroll
    for (int i = 0; i < 2; ++i)
#pragma unroll
        for (int j = 0; j < 8; ++j)
            part[w][l * 8 + i * 512 + j] = acc[i][j];
    __syncthreads();
    const float sc = 1.0f / 4096.0f;
#pragma unroll
    for (int i = 0; i < 4; ++i) {
        int c = t * 4 + i;
        float s = part[0][c] + part[1][c] + part[2][c] + part[3][c];
        atomicAdd(&gf[b * D + c], s * sc);
    }
}

// ---------------- out[row,e] = l2norm(Q_pre)[row,e] * gf[b,e]  (fp32 out) ---
__global__ __launch_bounds__(256) void q_scale(const ushort* __restrict__ Qp,
                                               const float* __restrict__ gf,
                                               float* __restrict__ out) {
    const int D = 1024;
    int row = blockIdx.x * 4 + (threadIdx.x >> 6);
    int l = threadIdx.x & 63;
    int b = row >> 12;
    const ushort* qr = &Qp[(size_t)row * D];
    float qf[4][4];
    float ss = 0.f;
#pragma unroll
    for (int i = 0; i < 4; ++i) {
        ushort4 q = *(const ushort4*)&qr[l * 4 + i * 256];
        qf[i][0] = b2f(q.x); qf[i][1] = b2f(q.y);
        qf[i][2] = b2f(q.z); qf[i][3] = b2f(q.w);
        ss += qf[i][0] * qf[i][0] + qf[i][1] * qf[i][1] +
              qf[i][2] * qf[i][2] + qf[i][3] * qf[i][3];
    }
#pragma unroll
    for (int off = 32; off; off >>= 1) ss += __shfl_xor(ss, off);
    float inv = 1.0f / fmaxf(sqrtf(ss), 1e-12f);
#pragma unroll
    for (int i = 0; i < 4; ++i) {
        float4 g = *(const float4*)&gf[b * D + l * 4 + i * 256];
        float4 o;
        o.x = qf[i][0] * inv * g.x;
        o.y = qf[i][1] * inv * g.y;
        o.z = qf[i][2] * inv * g.z;
        o.w = qf[i][3] * inv * g.w;
        *(float4*)&out[(size_t)row * D + l * 4 + i * 256] = o;
    }
}

extern "C" void kernel_launch(void* const* d_in, const int* in_sizes, int n_in,
                              void* d_out, int out_size, void* d_ws, size_t ws_size,
                              hipStream_t stream) {
    const float* x  = (const float*)d_in[0];
    const float* Wq = (const float*)d_in[1];
    const float* Wk = (const float*)d_in[2];
    const float* Wv = (const float*)d_in[3];
    float* out = (float*)d_out;

    const int Bb = 8, Nn = 4096, D = 1024;
    const int M = Bb * Nn;  // 32768 rows

    char* ws = (char*)d_ws;
    ushort* xb  = (ushort*)ws;                         // 67108864 B
    ushort* wqb = (ushort*)(ws + 67108864);            // 2097152 B  } contiguous
    ushort* wkb = (ushort*)(ws + 69206016);            // 2097152 B  } bf16 W's
    ushort* wvb = (ushort*)(ws + 71303168);            // 2097152 B  }
    ushort* P1  = (ushort*)(ws + 73400320);            // 67108864 B (Q_pre)
    float*  gf  = (float*)(ws + 140509184);            // 32768 B

    // d_out (134.2 MB) doubles as bf16 scratch for K_pre / V until q_scale.
    ushort* Kp = (ushort*)d_out;
    ushort* Vp = Kp + (size_t)M * D;

    hipMemsetAsync(gf, 0, Bb * D * sizeof(float), stream);

    f2b_kernel<<<2048, 256, 0, stream>>>(x, xb, (M * D) / 4);
    f2b3_kernel<<<1536, 256, 0, stream>>>(Wq, Wk, Wv, wqb, (D * D) / 4);

    gemm_bt10<<<512, 512, 0, stream>>>(xb, wkb, Kp);
    gemm_bt10<<<512, 512, 0, stream>>>(xb, wvb, Vp);
    kv_reduce<<<dim3(32, 8), 256, 0, stream>>>(Kp, Vp, gf);
    gemm_bt10<<<512, 512, 0, stream>>>(xb, wqb, P1);
    q_scale<<<M / 4, 256, 0, stream>>>(P1, gf, out);
}

// Round 14
// 289.195 us; speedup vs baseline: 1.1179x; 1.0446x over previous
//
#include <hip/hip_runtime.h>

typedef __attribute__((ext_vector_type(4))) float f32x4;
typedef __attribute__((ext_vector_type(8))) short bf16x8;

#define AS1 __attribute__((address_space(1)))
#define AS3 __attribute__((address_space(3)))

static __device__ __forceinline__ ushort f2b(float f) {
    uint u = __float_as_uint(f);
    uint r = (u + 0x7fffu + ((u >> 16) & 1u)) >> 16;
    return (ushort)r;
}
static __device__ __forceinline__ float b2f(ushort h) {
    return __uint_as_float(((uint)h) << 16);
}

// ---------------- fp32 -> bf16 convert (vectorized, grid-stride) -------------
__global__ __launch_bounds__(256) void f2b_kernel(const float* __restrict__ in,
                                                  ushort* __restrict__ out, int n4) {
    int i = blockIdx.x * blockDim.x + threadIdx.x;
    int stride = gridDim.x * blockDim.x;
    for (; i < n4; i += stride) {
        float4 v = ((const float4*)in)[i];
        ushort4 o;
        o.x = f2b(v.x); o.y = f2b(v.y); o.z = f2b(v.z); o.w = f2b(v.w);
        ((ushort4*)out)[i] = o;
    }
}

// ---- three equally-sized fp32 arrays -> one contiguous bf16 output ---------
__global__ __launch_bounds__(256) void f2b3_kernel(const float* __restrict__ A,
                                                   const float* __restrict__ B,
                                                   const float* __restrict__ C,
                                                   ushort* __restrict__ out, int n4) {
    int i = blockIdx.x * blockDim.x + threadIdx.x;
    int stride = gridDim.x * blockDim.x;
    for (; i < 3 * n4; i += stride) {
        const float* src = (i < n4) ? A : ((i < 2 * n4) ? B : C);
        int j = (i < n4) ? i : ((i < 2 * n4) ? i - n4 : i - 2 * n4);
        float4 v = ((const float4*)src)[j];
        ushort4 o;
        o.x = f2b(v.x); o.y = f2b(v.y); o.z = f2b(v.z); o.w = f2b(v.w);
        ((ushort4*)out)[i] = o;
    }
}

// ---------------- bf16 GEMM, C = A * B^T, 256x256, BK=64, 4-phase ----------
// R13's proven schedule (deep staging, ONE vmcnt(6)/K-tile, m201-canonical
// phase boundaries). Template MODE: 0 = Q (plain C write), 1 = K (C write +
// per-row sum-of-squares atomics into rnorm), 2 = V (no C write; fused
// K*V/||K|| column reduction into gf; Cin = Kp read back from L3).
__device__ __forceinline__ void stage_q(const ushort* __restrict__ G,
                                        ushort* Ls, int buf, int q, int rc0,
                                        int kcol, int w, int srow, int schunk) {
    ushort* dst = Ls + (buf * 4 + q) * 4096 + w * 512;  // wave-uniform base
    const ushort* src = G + (size_t)(rc0 + q * 64 + srow) * 1024 + kcol + schunk * 8;
    __builtin_amdgcn_global_load_lds((const AS1 void*)src, (AS3 void*)dst, 16, 0, 0);
}

#define PIN_PRE()  do { __builtin_amdgcn_s_barrier(); \
                        asm volatile("s_waitcnt lgkmcnt(0)" ::: "memory"); \
                        __builtin_amdgcn_s_setprio(1); } while (0)
#define PIN_POST() do { __builtin_amdgcn_s_setprio(0); \
                        __builtin_amdgcn_s_barrier(); } while (0)

template <int MODE>
__global__ __launch_bounds__(512, 2) void gemm_bt(const ushort* __restrict__ A,
                                                  const ushort* __restrict__ Bw,
                                                  ushort* __restrict__ C,
                                                  float* __restrict__ rnorm,
                                                  float* __restrict__ gf) {
    __shared__ ushort SMEM[69632];   // 128 KiB As|Bs (+8 KiB reduce scratch)
    ushort* As = SMEM;
    ushort* Bs = SMEM + 32768;

    // T1: XCD-chunked swizzle (nwg = 512)
    int nwg = gridDim.x, cpx = nwg >> 3, bid = blockIdx.x;
    int orig = (bid & 7) * cpx + (bid >> 3);
    int rt = orig >> 2, ct = orig & 3;
    int row0 = rt * 256, col0 = ct * 256;

    int t = threadIdx.x, l = t & 63, w = t >> 6;
    int wr = w >> 2, wc = w & 3;     // wave grid 2 (M) x 4 (N)
    int lr = l & 15, c16 = l >> 4;

    int srow = t >> 3;                     // staging row within quarter
    int schunk = (l & 7) ^ ((l >> 3) & 7); // staging source 16B chunk
    int o0 = ((c16 ^ (l & 7))) * 16;       // read slot bytes, k=0
    int o1 = o0 ^ 64;                      // k=1

    f32x4 acc[8][4] = {};
    bf16x8 a[4], a2[4], blo[2][2], bhi[2][2];

    const int NT = 16;  // K=1024 / 64
    // prologue: buf0 all 8 quarters; buf1: A-even (q0,q2) + B q0-3
#pragma unroll
    for (int q = 0; q < 4; ++q) stage_q(Bw, Bs, 0, q, col0, 0, w, srow, schunk);
#pragma unroll
    for (int q = 0; q < 4; ++q) stage_q(A, As, 0, q, row0, 0, w, srow, schunk);
    stage_q(A, As, 1, 0, row0, 64, w, srow, schunk);
    stage_q(A, As, 1, 2, row0, 64, w, srow, schunk);
#pragma unroll
    for (int q = 0; q < 4; ++q) stage_q(Bw, Bs, 1, q, col0, 64, w, srow, schunk);
    asm volatile("s_waitcnt vmcnt(6)" ::: "memory");  // seals buf0
    __builtin_amdgcn_s_barrier();

    for (int kt = 0; kt < NT; ++kt) {
        int buf = kt & 1, bn = buf ^ 1;
        int kc1 = (kt + 1) * 64, kc2 = (kt + 2) * 64;
        const char* AqL = (const char*)As + buf * 32768 + (2 * wr) * 8192 + lr * 128;
        const char* AqH = AqL + 8192;
        const char* Bq  = (const char*)Bs + buf * 32768 + wc * 8192 + lr * 128;

        // ===== P1 [mlo x nlo]: read a-lo(8) + b-lo(4); stage A-odd(kt+1) ====
#pragma unroll
        for (int mf = 0; mf < 4; ++mf) {
            a[mf]  = *(const bf16x8*)(AqL + mf * 2048 + o0);
            a2[mf] = *(const bf16x8*)(AqL + mf * 2048 + o1);
        }
#pragma unroll
        for (int nf = 0; nf < 2; ++nf) {
            blo[nf][0] = *(const bf16x8*)(Bq + nf * 2048 + o0);
            blo[nf][1] = *(const bf16x8*)(Bq + nf * 2048 + o1);
        }
        if (kt + 1 < NT) {
            stage_q(A, As, bn, 1, row0, kc1, w, srow, schunk);
            stage_q(A, As, bn, 3, row0, kc1, w, srow, schunk);
        }
        asm volatile("s_waitcnt lgkmcnt(8)" ::: "memory");
        PIN_PRE();
#pragma unroll
        for (int mf = 0; mf < 4; ++mf)
#pragma unroll
            for (int nf = 0; nf < 2; ++nf) {
                acc[mf][nf] = __builtin_amdgcn_mfma_f32_16x16x32_bf16(a[mf],  blo[nf][0], acc[mf][nf], 0, 0, 0);
                acc[mf][nf] = __builtin_amdgcn_mfma_f32_16x16x32_bf16(a2[mf], blo[nf][1], acc[mf][nf], 0, 0, 0);
            }
        PIN_POST();

        // ===== P2 [mlo x nhi]: read b-hi(4); stage A-even(kt+2) =============
#pragma unroll
        for (int nf = 0; nf < 2; ++nf) {
            bhi[nf][0] = *(const bf16x8*)(Bq + (2 + nf) * 2048 + o0);
            bhi[nf][1] = *(const bf16x8*)(Bq + (2 + nf) * 2048 + o1);
        }
        if (kt + 2 < NT) {
            stage_q(A, As, buf, 0, row0, kc2, w, srow, schunk);
            stage_q(A, As, buf, 2, row0, kc2, w, srow, schunk);
        }
        PIN_PRE();
#pragma unroll
        for (int mf = 0; mf < 4; ++mf)
#pragma unroll
            for (int nf = 0; nf < 2; ++nf) {
                acc[mf][2 + nf] = __builtin_amdgcn_mfma_f32_16x16x32_bf16(a[mf],  bhi[nf][0], acc[mf][2 + nf], 0, 0, 0);
                acc[mf][2 + nf] = __builtin_amdgcn_mfma_f32_16x16x32_bf16(a2[mf], bhi[nf][1], acc[mf][2 + nf], 0, 0, 0);
            }
        PIN_POST();

        // ===== P3 [mhi x nlo]: read a-hi(8); stage B01(kt+2) ================
#pragma unroll
        for (int mf = 0; mf < 4; ++mf) {
            a[mf]  = *(const bf16x8*)(AqH + mf * 2048 + o0);
            a2[mf] = *(const bf16x8*)(AqH + mf * 2048 + o1);
        }
        if (kt + 2 < NT) {
            stage_q(Bw, Bs, buf, 0, col0, kc2, w, srow, schunk);
            stage_q(Bw, Bs, buf, 1, col0, kc2, w, srow, schunk);
        }
        PIN_PRE();
#pragma unroll
        for (int mf = 0; mf < 4; ++mf)
#pragma unroll
            for (int nf = 0; nf < 2; ++nf) {
                acc[4 + mf][nf] = __builtin_amdgcn_mfma_f32_16x16x32_bf16(a[mf],  blo[nf][0], acc[4 + mf][nf], 0, 0, 0);
                acc[4 + mf][nf] = __builtin_amdgcn_mfma_f32_16x16x32_bf16(a2[mf], blo[nf][1], acc[4 + mf][nf], 0, 0, 0);
            }
        PIN_POST();

        // ===== P4 [mhi x nhi]: stage B23(kt+2); ONE vmcnt checkpoint ========
        if (kt + 2 < NT) {
            stage_q(Bw, Bs, buf, 2, col0, kc2, w, srow, schunk);
            stage_q(Bw, Bs, buf, 3, col0, kc2, w, srow, schunk);
        }
        if (kt + 2 < NT)      asm volatile("s_waitcnt vmcnt(6)" ::: "memory");
        else if (kt + 1 < NT) asm volatile("s_waitcnt vmcnt(0)" ::: "memory");
        __builtin_amdgcn_s_barrier();
        __builtin_amdgcn_s_setprio(1);
#pragma unroll
        for (int mf = 0; mf < 4; ++mf)
#pragma unroll
            for (int nf = 0; nf < 2; ++nf) {
                acc[4 + mf][2 + nf] = __builtin_amdgcn_mfma_f32_16x16x32_bf16(a[mf],  bhi[nf][0], acc[4 + mf][2 + nf], 0, 0, 0);
                acc[4 + mf][2 + nf] = __builtin_amdgcn_mfma_f32_16x16x32_bf16(a2[mf], bhi[nf][1], acc[4 + mf][2 + nf], 0, 0, 0);
            }
        PIN_POST();
    }

    // ---- MODE 1 (K): per-row sum-of-squares -> rnorm atomics (from fp32 acc)
    if (MODE == 1) {
#pragma unroll
        for (int m = 0; m < 8; ++m)
#pragma unroll
            for (int j = 0; j < 4; ++j) {
                float s = acc[m][0][j] * acc[m][0][j] + acc[m][1][j] * acc[m][1][j]
                        + acc[m][2][j] * acc[m][2][j] + acc[m][3][j] * acc[m][3][j];
                s += __shfl_xor(s, 1); s += __shfl_xor(s, 2);
                s += __shfl_xor(s, 4); s += __shfl_xor(s, 8);
                if (lr == 0)
                    atomicAdd(&rnorm[row0 + wr * 128 + m * 16 + c16 * 4 + j], s);
            }
    }

    // ---- C tile -> SMEM (all modes) ----------------------------------------
#pragma unroll
    for (int m = 0; m < 8; ++m) {
        int lrow = wr * 128 + m * 16 + c16 * 4;
#pragma unroll
        for (int n = 0; n < 4; ++n) {
            int lcol = wc * 64 + n * 16 + lr;
#pragma unroll
            for (int j = 0; j < 4; ++j)
                SMEM[(lrow + j) * 256 + lcol] = f2b(acc[m][n][j]);
        }
    }
    __syncthreads();

    if (MODE != 2) {
        // coalesced 16B global stores of the C tile
#pragma unroll
        for (int g = 0; g < 16; ++g) {
            int ch = g * 512 + t;           // 16B-chunk index in the 256x256 tile
            int r = ch >> 5, c8 = ch & 31;
            bf16x8 v = *(const bf16x8*)&SMEM[ch * 8];
            *(bf16x8*)&C[(size_t)(row0 + r) * 1024 + col0 + c8 * 8] = v;
        }
    } else {
        // ---- MODE 2 (V): fused gf reduce; V slab is in SMEM, K from global -
        float* part = (float*)(SMEM + 65536);   // [8][256] f32
        float gp0 = 0.f, gp1 = 0.f, gp2 = 0.f, gp3 = 0.f;
        int r0l = w * 32;
        for (int r = r0l; r < r0l + 32; ++r) {
            float ss = rnorm[row0 + r];
            float inv = 1.0f / fmaxf(sqrtf(ss), 1e-12f);
            ushort4 kv = *(const ushort4*)&C[(size_t)(row0 + r) * 1024 + col0 + l * 4];
            ushort4 vv = *(const ushort4*)&SMEM[r * 256 + l * 4];
            gp0 += b2f(kv.x) * inv * b2f(vv.x);
            gp1 += b2f(kv.y) * inv * b2f(vv.y);
            gp2 += b2f(kv.z) * inv * b2f(vv.z);
            gp3 += b2f(kv.w) * inv * b2f(vv.w);
        }
        part[w * 256 + l * 4 + 0] = gp0;
        part[w * 256 + l * 4 + 1] = gp1;
        part[w * 256 + l * 4 + 2] = gp2;
        part[w * 256 + l * 4 + 3] = gp3;
        __syncthreads();
        if (t < 256) {
            float s = 0.f;
#pragma unroll
            for (int ww = 0; ww < 8; ++ww) s += part[ww * 256 + t];
            int b = row0 >> 12;
            atomicAdd(&gf[b * 1024 + col0 + t], s * (1.0f / 4096.0f));
        }
    }
}

// ---------------- out[row,e] = l2norm(Q_pre)[row,e] * gf[b,e]  (fp32 out) ---
__global__ __launch_bounds__(256) void q_scale(const ushort* __restrict__ Qp,
                                               const float* __restrict__ gf,
                                               float* __restrict__ out) {
    const int D = 1024;
    int row = blockIdx.x * 4 + (threadIdx.x >> 6);
    int l = threadIdx.x & 63;
    int b = row >> 12;
    const ushort* qr = &Qp[(size_t)row * D];
    float qf[4][4];
    float ss = 0.f;
#pragma unroll
    for (int i = 0; i < 4; ++i) {
        ushort4 q = *(const ushort4*)&qr[l * 4 + i * 256];
        qf[i][0] = b2f(q.x); qf[i][1] = b2f(q.y);
        qf[i][2] = b2f(q.z); qf[i][3] = b2f(q.w);
        ss += qf[i][0] * qf[i][0] + qf[i][1] * qf[i][1] +
              qf[i][2] * qf[i][2] + qf[i][3] * qf[i][3];
    }
#pragma unroll
    for (int off = 32; off; off >>= 1) ss += __shfl_xor(ss, off);
    float inv = 1.0f / fmaxf(sqrtf(ss), 1e-12f);
#pragma unroll
    for (int i = 0; i < 4; ++i) {
        float4 g = *(const float4*)&gf[b * D + l * 4 + i * 256];
        float4 o;
        o.x = qf[i][0] * inv * g.x;
        o.y = qf[i][1] * inv * g.y;
        o.z = qf[i][2] * inv * g.z;
        o.w = qf[i][3] * inv * g.w;
        *(float4*)&out[(size_t)row * D + l * 4 + i * 256] = o;
    }
}

extern "C" void kernel_launch(void* const* d_in, const int* in_sizes, int n_in,
                              void* d_out, int out_size, void* d_ws, size_t ws_size,
                              hipStream_t stream) {
    const float* x  = (const float*)d_in[0];
    const float* Wq = (const float*)d_in[1];
    const float* Wk = (const float*)d_in[2];
    const float* Wv = (const float*)d_in[3];
    float* out = (float*)d_out;

    const int Bb = 8, Nn = 4096, D = 1024;
    const int M = Bb * Nn;  // 32768 rows

    char* ws = (char*)d_ws;
    ushort* xb  = (ushort*)ws;                         // 67108864 B
    ushort* wqb = (ushort*)(ws + 67108864);            // 2097152 B  } contiguous
    ushort* wkb = (ushort*)(ws + 69206016);            // 2097152 B  } bf16 W's
    ushort* wvb = (ushort*)(ws + 71303168);            // 2097152 B  }
    ushort* P1  = (ushort*)(ws + 73400320);            // 67108864 B (Q_pre)
    float*  gf  = (float*)(ws + 140509184);            // 32768 B

    // d_out (128 MB fp32): lower 64 MB = Kp (bf16), +64 MB = rnorm (128 KB).
    // Both dead before q_scale overwrites d_out with the final fp32 output.
    ushort* Kp = (ushort*)d_out;
    float* rnorm = (float*)((char*)d_out + 67108864);

    hipMemsetAsync(gf, 0, Bb * D * sizeof(float), stream);
    hipMemsetAsync(rnorm, 0, M * sizeof(float), stream);

    f2b_kernel<<<2048, 256, 0, stream>>>(x, xb, (M * D) / 4);
    f2b3_kernel<<<1536, 256, 0, stream>>>(Wq, Wk, Wv, wqb, (D * D) / 4);

    gemm_bt<1><<<512, 512, 0, stream>>>(xb, wkb, Kp, rnorm, nullptr);   // K + rnorm
    gemm_bt<2><<<512, 512, 0, stream>>>(xb, wvb, Kp, rnorm, gf);        // V -> gf
    gemm_bt<0><<<512, 512, 0, stream>>>(xb, wqb, P1, nullptr, nullptr); // Q
    q_scale<<<M / 4, 256, 0, stream>>>(P1, gf, out);
}

// Round 15
// 283.208 us; speedup vs baseline: 1.1416x; 1.0211x over previous
//
#include <hip/hip_runtime.h>

typedef __attribute__((ext_vector_type(4))) float f32x4;
typedef __attribute__((ext_vector_type(8))) short bf16x8;

#define AS1 __attribute__((address_space(1)))
#define AS3 __attribute__((address_space(3)))

static __device__ __forceinline__ ushort f2b(float f) {
    uint u = __float_as_uint(f);
    uint r = (u + 0x7fffu + ((u >> 16) & 1u)) >> 16;
    return (ushort)r;
}
static __device__ __forceinline__ float b2f(ushort h) {
    return __uint_as_float(((uint)h) << 16);
}

// ---------------- fp32 -> bf16 convert (vectorized, grid-stride) -------------
__global__ __launch_bounds__(256) void f2b_kernel(const float* __restrict__ in,
                                                  ushort* __restrict__ out, int n4) {
    int i = blockIdx.x * blockDim.x + threadIdx.x;
    int stride = gridDim.x * blockDim.x;
    for (; i < n4; i += stride) {
        float4 v = ((const float4*)in)[i];
        ushort4 o;
        o.x = f2b(v.x); o.y = f2b(v.y); o.z = f2b(v.z); o.w = f2b(v.w);
        ((ushort4*)out)[i] = o;
    }
}

// ---- three equally-sized fp32 arrays -> one contiguous bf16 output ---------
__global__ __launch_bounds__(256) void f2b3_kernel(const float* __restrict__ A,
                                                   const float* __restrict__ B,
                                                   const float* __restrict__ C,
                                                   ushort* __restrict__ out, int n4) {
    int i = blockIdx.x * blockDim.x + threadIdx.x;
    int stride = gridDim.x * blockDim.x;
    for (; i < 3 * n4; i += stride) {
        const float* src = (i < n4) ? A : ((i < 2 * n4) ? B : C);
        int j = (i < n4) ? i : ((i < 2 * n4) ? i - n4 : i - 2 * n4);
        float4 v = ((const float4*)src)[j];
        ushort4 o;
        o.x = f2b(v.x); o.y = f2b(v.y); o.z = f2b(v.z); o.w = f2b(v.w);
        ((ushort4*)out)[i] = o;
    }
}

// ---------------- bf16 GEMM, C = A * B^T, 256x256, BK=64, 4-phase ----------
// R13's proven schedule. SMEM held at EXACTLY 128 KiB (R14 lesson: >128 KiB
// LDS allocation cost ~17% on the whole K-loop). MODE: 0 = Q (plain C write),
// 1 = K (C write + per-row sum-of-squares atomics into rnorm), 2 = V
// (no C write; fused sum_n K*V/||K|| -> gf, V taken from fp32 accumulators,
// K re-read from global (L3), cross-wave combine in 2 KiB of the freed SMEM).
__device__ __forceinline__ void stage_q(const ushort* __restrict__ G,
                                        ushort* Ls, int buf, int q, int rc0,
                                        int kcol, int w, int srow, int schunk) {
    ushort* dst = Ls + (buf * 4 + q) * 4096 + w * 512;  // wave-uniform base
    const ushort* src = G + (size_t)(rc0 + q * 64 + srow) * 1024 + kcol + schunk * 8;
    __builtin_amdgcn_global_load_lds((const AS1 void*)src, (AS3 void*)dst, 16, 0, 0);
}

#define PIN_PRE()  do { __builtin_amdgcn_s_barrier(); \
                        asm volatile("s_waitcnt lgkmcnt(0)" ::: "memory"); \
                        __builtin_amdgcn_s_setprio(1); } while (0)
#define PIN_POST() do { __builtin_amdgcn_s_setprio(0); \
                        __builtin_amdgcn_s_barrier(); } while (0)

template <int MODE>
__global__ __launch_bounds__(512, 2) void gemm_bt(const ushort* __restrict__ A,
                                                  const ushort* __restrict__ Bw,
                                                  ushort* __restrict__ C,
                                                  float* __restrict__ rnorm,
                                                  float* __restrict__ gf) {
    __shared__ ushort SMEM[65536];   // 128 KiB exactly: As | Bs
    ushort* As = SMEM;
    ushort* Bs = SMEM + 32768;

    // T1: XCD-chunked swizzle (nwg = 512)
    int nwg = gridDim.x, cpx = nwg >> 3, bid = blockIdx.x;
    int orig = (bid & 7) * cpx + (bid >> 3);
    int rt = orig >> 2, ct = orig & 3;
    int row0 = rt * 256, col0 = ct * 256;

    int t = threadIdx.x, l = t & 63, w = t >> 6;
    int wr = w >> 2, wc = w & 3;     // wave grid 2 (M) x 4 (N)
    int lr = l & 15, c16 = l >> 4;

    int srow = t >> 3;                     // staging row within quarter
    int schunk = (l & 7) ^ ((l >> 3) & 7); // staging source 16B chunk
    int o0 = ((c16 ^ (l & 7))) * 16;       // read slot bytes, k=0
    int o1 = o0 ^ 64;                      // k=1

    f32x4 acc[8][4] = {};
    bf16x8 a[4], a2[4], blo[2][2], bhi[2][2];

    const int NT = 16;  // K=1024 / 64
    // prologue: buf0 all 8 quarters; buf1: A-even (q0,q2) + B q0-3
#pragma unroll
    for (int q = 0; q < 4; ++q) stage_q(Bw, Bs, 0, q, col0, 0, w, srow, schunk);
#pragma unroll
    for (int q = 0; q < 4; ++q) stage_q(A, As, 0, q, row0, 0, w, srow, schunk);
    stage_q(A, As, 1, 0, row0, 64, w, srow, schunk);
    stage_q(A, As, 1, 2, row0, 64, w, srow, schunk);
#pragma unroll
    for (int q = 0; q < 4; ++q) stage_q(Bw, Bs, 1, q, col0, 64, w, srow, schunk);
    asm volatile("s_waitcnt vmcnt(6)" ::: "memory");  // seals buf0
    __builtin_amdgcn_s_barrier();

    for (int kt = 0; kt < NT; ++kt) {
        int buf = kt & 1, bn = buf ^ 1;
        int kc1 = (kt + 1) * 64, kc2 = (kt + 2) * 64;
        const char* AqL = (const char*)As + buf * 32768 + (2 * wr) * 8192 + lr * 128;
        const char* AqH = AqL + 8192;
        const char* Bq  = (const char*)Bs + buf * 32768 + wc * 8192 + lr * 128;

        // ===== P1 [mlo x nlo]: read a-lo(8) + b-lo(4); stage A-odd(kt+1) ====
#pragma unroll
        for (int mf = 0; mf < 4; ++mf) {
            a[mf]  = *(const bf16x8*)(AqL + mf * 2048 + o0);
            a2[mf] = *(const bf16x8*)(AqL + mf * 2048 + o1);
        }
#pragma unroll
        for (int nf = 0; nf < 2; ++nf) {
            blo[nf][0] = *(const bf16x8*)(Bq + nf * 2048 + o0);
            blo[nf][1] = *(const bf16x8*)(Bq + nf * 2048 + o1);
        }
        if (kt + 1 < NT) {
            stage_q(A, As, bn, 1, row0, kc1, w, srow, schunk);
            stage_q(A, As, bn, 3, row0, kc1, w, srow, schunk);
        }
        asm volatile("s_waitcnt lgkmcnt(8)" ::: "memory");
        PIN_PRE();
#pragma unroll
        for (int mf = 0; mf < 4; ++mf)
#pragma unroll
            for (int nf = 0; nf < 2; ++nf) {
                acc[mf][nf] = __builtin_amdgcn_mfma_f32_16x16x32_bf16(a[mf],  blo[nf][0], acc[mf][nf], 0, 0, 0);
                acc[mf][nf] = __builtin_amdgcn_mfma_f32_16x16x32_bf16(a2[mf], blo[nf][1], acc[mf][nf], 0, 0, 0);
            }
        PIN_POST();

        // ===== P2 [mlo x nhi]: read b-hi(4); stage A-even(kt+2) =============
#pragma unroll
        for (int nf = 0; nf < 2; ++nf) {
            bhi[nf][0] = *(const bf16x8*)(Bq + (2 + nf) * 2048 + o0);
            bhi[nf][1] = *(const bf16x8*)(Bq + (2 + nf) * 2048 + o1);
        }
        if (kt + 2 < NT) {
            stage_q(A, As, buf, 0, row0, kc2, w, srow, schunk);
            stage_q(A, As, buf, 2, row0, kc2, w, srow, schunk);
        }
        PIN_PRE();
#pragma unroll
        for (int mf = 0; mf < 4; ++mf)
#pragma unroll
            for (int nf = 0; nf < 2; ++nf) {
                acc[mf][2 + nf] = __builtin_amdgcn_mfma_f32_16x16x32_bf16(a[mf],  bhi[nf][0], acc[mf][2 + nf], 0, 0, 0);
                acc[mf][2 + nf] = __builtin_amdgcn_mfma_f32_16x16x32_bf16(a2[mf], bhi[nf][1], acc[mf][2 + nf], 0, 0, 0);
            }
        PIN_POST();

        // ===== P3 [mhi x nlo]: read a-hi(8); stage B01(kt+2) ================
#pragma unroll
        for (int mf = 0; mf < 4; ++mf) {
            a[mf]  = *(const bf16x8*)(AqH + mf * 2048 + o0);
            a2[mf] = *(const bf16x8*)(AqH + mf * 2048 + o1);
        }
        if (kt + 2 < NT) {
            stage_q(Bw, Bs, buf, 0, col0, kc2, w, srow, schunk);
            stage_q(Bw, Bs, buf, 1, col0, kc2, w, srow, schunk);
        }
        PIN_PRE();
#pragma unroll
        for (int mf = 0; mf < 4; ++mf)
#pragma unroll
            for (int nf = 0; nf < 2; ++nf) {
                acc[4 + mf][nf] = __builtin_amdgcn_mfma_f32_16x16x32_bf16(a[mf],  blo[nf][0], acc[4 + mf][nf], 0, 0, 0);
                acc[4 + mf][nf] = __builtin_amdgcn_mfma_f32_16x16x32_bf16(a2[mf], blo[nf][1], acc[4 + mf][nf], 0, 0, 0);
            }
        PIN_POST();

        // ===== P4 [mhi x nhi]: stage B23(kt+2); ONE vmcnt checkpoint ========
        if (kt + 2 < NT) {
            stage_q(Bw, Bs, buf, 2, col0, kc2, w, srow, schunk);
            stage_q(Bw, Bs, buf, 3, col0, kc2, w, srow, schunk);
        }
        if (kt + 2 < NT)      asm volatile("s_waitcnt vmcnt(6)" ::: "memory");
        else if (kt + 1 < NT) asm volatile("s_waitcnt vmcnt(0)" ::: "memory");
        __builtin_amdgcn_s_barrier();
        __builtin_amdgcn_s_setprio(1);
#pragma unroll
        for (int mf = 0; mf < 4; ++mf)
#pragma unroll
            for (int nf = 0; nf < 2; ++nf) {
                acc[4 + mf][2 + nf] = __builtin_amdgcn_mfma_f32_16x16x32_bf16(a[mf],  bhi[nf][0], acc[4 + mf][2 + nf], 0, 0, 0);
                acc[4 + mf][2 + nf] = __builtin_amdgcn_mfma_f32_16x16x32_bf16(a2[mf], bhi[nf][1], acc[4 + mf][2 + nf], 0, 0, 0);
            }
        PIN_POST();
    }

    // ---- MODE 1 (K): per-row sum-of-squares -> rnorm atomics (fp32 acc) ----
    if (MODE == 1) {
#pragma unroll
        for (int m = 0; m < 8; ++m)
#pragma unroll
            for (int j = 0; j < 4; ++j) {
                float s = acc[m][0][j] * acc[m][0][j] + acc[m][1][j] * acc[m][1][j]
                        + acc[m][2][j] * acc[m][2][j] + acc[m][3][j] * acc[m][3][j];
                s += __shfl_xor(s, 1); s += __shfl_xor(s, 2);
                s += __shfl_xor(s, 4); s += __shfl_xor(s, 8);
                if (lr == 0)
                    atomicAdd(&rnorm[row0 + wr * 128 + m * 16 + c16 * 4 + j], s);
            }
    }

    if (MODE != 2) {
        // ---- C tile -> SMEM, then coalesced 16B global stores --------------
#pragma unroll
        for (int m = 0; m < 8; ++m) {
            int lrow = wr * 128 + m * 16 + c16 * 4;
#pragma unroll
            for (int n = 0; n < 4; ++n) {
                int lcol = wc * 64 + n * 16 + lr;
#pragma unroll
                for (int j = 0; j < 4; ++j)
                    SMEM[(lrow + j) * 256 + lcol] = f2b(acc[m][n][j]);
            }
        }
        __syncthreads();
#pragma unroll
        for (int g = 0; g < 16; ++g) {
            int ch = g * 512 + t;           // 16B-chunk index in the 256x256 tile
            int r = ch >> 5, c8 = ch & 31;
            bf16x8 v = *(const bf16x8*)&SMEM[ch * 8];
            *(bf16x8*)&C[(size_t)(row0 + r) * 1024 + col0 + c8 * 8] = v;
        }
    } else {
        // ---- MODE 2 (V): register-sourced fused gf reduce -------------------
        // V = fp32 acc at (row = wr*128+m*16+c16*4+j, col = wc*64+n*16+lr);
        // K re-read from global (L3-hot); butterfly over c16; 2 KiB combine.
        float p[4] = {0.f, 0.f, 0.f, 0.f};
#pragma unroll
        for (int m = 0; m < 8; ++m)
#pragma unroll
            for (int j = 0; j < 4; ++j) {
                int r = wr * 128 + m * 16 + c16 * 4 + j;
                float inv = 1.0f / fmaxf(sqrtf(rnorm[row0 + r]), 1e-12f);
                const ushort* krow = &C[(size_t)(row0 + r) * 1024 + col0];
#pragma unroll
                for (int n = 0; n < 4; ++n)
                    p[n] += b2f(krow[wc * 64 + n * 16 + lr]) * inv * acc[m][n][j];
            }
#pragma unroll
        for (int n = 0; n < 4; ++n) {
            p[n] += __shfl_xor(p[n], 16);
            p[n] += __shfl_xor(p[n], 32);
        }
        float* part = (float*)SMEM;   // [8 waves][16 lr][4 n] = 2 KiB
        if (l < 16) {
#pragma unroll
            for (int n = 0; n < 4; ++n) part[(w * 16 + lr) * 4 + n] = p[n];
        }
        __syncthreads();
        if (t < 256) {
            int wcq = t >> 6, nq = (t >> 4) & 3, lrq = t & 15;
            float s = part[((wcq) * 16 + lrq) * 4 + nq]
                    + part[((4 + wcq) * 16 + lrq) * 4 + nq];
            int b = row0 >> 12;
            atomicAdd(&gf[b * 1024 + col0 + t], s * (1.0f / 4096.0f));
        }
    }
}

// ---------------- out[row,e] = l2norm(Q_pre)[row,e] * gf[b,e]  (fp32 out) ---
__global__ __launch_bounds__(256) void q_scale(const ushort* __restrict__ Qp,
                                               const float* __restrict__ gf,
                                               float* __restrict__ out) {
    const int D = 1024;
    int row = blockIdx.x * 4 + (threadIdx.x >> 6);
    int l = threadIdx.x & 63;
    int b = row >> 12;
    const ushort* qr = &Qp[(size_t)row * D];
    float qf[4][4];
    float ss = 0.f;
#pragma unroll
    for (int i = 0; i < 4; ++i) {
        ushort4 q = *(const ushort4*)&qr[l * 4 + i * 256];
        qf[i][0] = b2f(q.x); qf[i][1] = b2f(q.y);
        qf[i][2] = b2f(q.z); qf[i][3] = b2f(q.w);
        ss += qf[i][0] * qf[i][0] + qf[i][1] * qf[i][1] +
              qf[i][2] * qf[i][2] + qf[i][3] * qf[i][3];
    }
#pragma unroll
    for (int off = 32; off; off >>= 1) ss += __shfl_xor(ss, off);
    float inv = 1.0f / fmaxf(sqrtf(ss), 1e-12f);
#pragma unroll
    for (int i = 0; i < 4; ++i) {
        float4 g = *(const float4*)&gf[b * D + l * 4 + i * 256];
        float4 o;
        o.x = qf[i][0] * inv * g.x;
        o.y = qf[i][1] * inv * g.y;
        o.z = qf[i][2] * inv * g.z;
        o.w = qf[i][3] * inv * g.w;
        *(float4*)&out[(size_t)row * D + l * 4 + i * 256] = o;
    }
}

extern "C" void kernel_launch(void* const* d_in, const int* in_sizes, int n_in,
                              void* d_out, int out_size, void* d_ws, size_t ws_size,
                              hipStream_t stream) {
    const float* x  = (const float*)d_in[0];
    const float* Wq = (const float*)d_in[1];
    const float* Wk = (const float*)d_in[2];
    const float* Wv = (const float*)d_in[3];
    float* out = (float*)d_out;

    const int Bb = 8, Nn = 4096, D = 1024;
    const int M = Bb * Nn;  // 32768 rows

    char* ws = (char*)d_ws;
    ushort* xb  = (ushort*)ws;                         // 67108864 B
    ushort* wqb = (ushort*)(ws + 67108864);            // 2097152 B  } contiguous
    ushort* wkb = (ushort*)(ws + 69206016);            // 2097152 B  } bf16 W's
    ushort* wvb = (ushort*)(ws + 71303168);            // 2097152 B  }
    ushort* P1  = (ushort*)(ws + 73400320);            // 67108864 B (Q_pre)
    float*  gf  = (float*)(ws + 140509184);            // 32768 B

    // d_out (128 MB fp32): lower 64 MB = Kp (bf16), +64 MB = rnorm (128 KB).
    // Both dead before q_scale overwrites d_out with the final fp32 output.
    ushort* Kp = (ushort*)d_out;
    float* rnorm = (float*)((char*)d_out + 67108864);

    hipMemsetAsync(gf, 0, Bb * D * sizeof(float), stream);
    hipMemsetAsync(rnorm, 0, M * sizeof(float), stream);

    f2b_kernel<<<2048, 256, 0, stream>>>(x, xb, (M * D) / 4);
    f2b3_kernel<<<1536, 256, 0, stream>>>(Wq, Wk, Wv, wqb, (D * D) / 4);

    gemm_bt<1><<<512, 512, 0, stream>>>(xb, wkb, Kp, rnorm, nullptr);   // K + rnorm
    gemm_bt<2><<<512, 512, 0, stream>>>(xb, wvb, Kp, rnorm, gf);        // V -> gf
    gemm_bt<0><<<512, 512, 0, stream>>>(xb, wqb, P1, nullptr, nullptr); // Q
    q_scale<<<M / 4, 256, 0, stream>>>(P1, gf, out);
}